// Round 6
// baseline (307.027 us; speedup 1.0000x reference)
//
#include <hip/hip_runtime.h>
#include <math.h>

#define NB 4
#define NC 4
#define NF 257
#define NFR 1024
#define NTOT (NB * NC * NF * NFR)
#define NBC (NB * NC)
#define EPSV 1e-3f
#define EPS_MODEL 1e-5f
#define NCHUNK 32

// Module-scope scratch: allocated at load, graph-capture safe, fully
// rewritten every call.
__device__ float g_Spart[NCHUNK * NBC * NFR];  // 2 MB partial column sums
__device__ float g_S[NBC * NFR];               // S[b,c,n] = sum_f |X[b,c,f,n]|^2

// Pair-of-frames vector type; elementwise ops shaped for v_pk_*_f32 codegen.
struct f2 { float x, y; };
__device__ __forceinline__ f2 operator+(f2 a, f2 b) { return {a.x + b.x, a.y + b.y}; }
__device__ __forceinline__ f2 operator-(f2 a, f2 b) { return {a.x - b.x, a.y - b.y}; }
__device__ __forceinline__ f2 operator*(f2 a, f2 b) { return {a.x * b.x, a.y * b.y}; }
__device__ __forceinline__ f2 operator*(f2 a, float s) { return {a.x * s, a.y * s}; }
__device__ __forceinline__ void operator+=(f2& a, f2 b) { a.x += b.x; a.y += b.y; }
__device__ __forceinline__ void operator-=(f2& a, f2 b) { a.x -= b.x; a.y -= b.y; }

// Wave-wide sum via DPP (VALU pipe). Lane 63 holds the sum.
__device__ __forceinline__ float dpp_red_sum(float v) {
  v += __int_as_float(__builtin_amdgcn_update_dpp(0, __float_as_int(v), 0x111, 0xf, 0xf, true)); // row_shr:1
  v += __int_as_float(__builtin_amdgcn_update_dpp(0, __float_as_int(v), 0x112, 0xf, 0xf, true)); // row_shr:2
  v += __int_as_float(__builtin_amdgcn_update_dpp(0, __float_as_int(v), 0x114, 0xf, 0xf, true)); // row_shr:4
  v += __int_as_float(__builtin_amdgcn_update_dpp(0, __float_as_int(v), 0x118, 0xf, 0xf, true)); // row_shr:8
  v += __int_as_float(__builtin_amdgcn_update_dpp(0, __float_as_int(v), 0x142, 0xa, 0xf, true)); // row_bcast:15
  v += __int_as_float(__builtin_amdgcn_update_dpp(0, __float_as_int(v), 0x143, 0xc, 0xf, true)); // row_bcast:31
  return v;
}

// ---------------------------------------------------------------------------
// K1: partial column sums, float4-vectorized, 512 blocks (full GPU).
// grid (16, 32): x covers bc*256 quad-frames, y = freq chunk of 9.
// ---------------------------------------------------------------------------
__global__ __launch_bounds__(256) void k_colsum(const float* __restrict__ Xr,
                                                const float* __restrict__ Xi) {
  int u = blockIdx.x * 256 + threadIdx.x;  // bc*256 + q
  int fc = blockIdx.y;
  int f0 = fc * 9;
  int f1 = f0 + 9; if (f1 > NF) f1 = NF;
  int bc = u >> 8, q = u & 255;
  float4 s = make_float4(0.f, 0.f, 0.f, 0.f);
  for (int f = f0; f < f1; ++f) {
    float4 a = reinterpret_cast<const float4*>(Xr + (bc * NF + f) * NFR)[q];
    float4 b = reinterpret_cast<const float4*>(Xi + (bc * NF + f) * NFR)[q];
    s.x += a.x * a.x + b.x * b.x;
    s.y += a.y * a.y + b.y * b.y;
    s.z += a.z * a.z + b.z * b.z;
    s.w += a.w * a.w + b.w * b.w;
  }
  reinterpret_cast<float4*>(g_Spart + fc * (NBC * NFR) + bc * NFR)[q] = s;
}

// K1b: reduce the 32 partials -> g_S. 16 blocks.
__global__ __launch_bounds__(256) void k_red() {
  int u = blockIdx.x * 256 + threadIdx.x;  // quad id < 4096
  float4 s = make_float4(0.f, 0.f, 0.f, 0.f);
#pragma unroll
  for (int fc = 0; fc < NCHUNK; ++fc) {
    float4 a = reinterpret_cast<const float4*>(g_Spart + fc * (NBC * NFR))[u];
    s.x += a.x; s.y += a.y; s.z += a.z; s.w += a.w;
  }
  reinterpret_cast<float4*>(g_S)[u] = s;
}

// Block-level reduction of 12 partials (proven in round 5).
__device__ __forceinline__ void block_reduce12(float* __restrict__ p,
                                               float (*red)[4][12], int buf,
                                               int lane, int wvid,
                                               float* __restrict__ s) {
#pragma unroll
  for (int k = 0; k < 12; ++k) p[k] = dpp_red_sum(p[k]);
  if (lane == 63) {
    float4* dst = reinterpret_cast<float4*>(&red[buf][wvid][0]);
    dst[0] = make_float4(p[0], p[1], p[2], p[3]);
    dst[1] = make_float4(p[4], p[5], p[6], p[7]);
    dst[2] = make_float4(p[8], p[9], p[10], p[11]);
  }
  __syncthreads();
  const float4* r = reinterpret_cast<const float4*>(&red[buf][0][0]);
#pragma unroll
  for (int k = 0; k < 3; ++k) {
    float4 a = r[0 + k], b = r[3 + k], c = r[6 + k], d = r[9 + k];
    s[4 * k + 0] = a.x + b.x + c.x + d.x;
    s[4 * k + 1] = a.y + b.y + c.y + d.y;
    s[4 * k + 2] = a.z + b.z + c.z + d.z;
    s[4 * k + 3] = a.w + b.w + c.w + d.w;
  }
}

// ---------------------------------------------------------------------------
// Main: one block per (b,f). Frames 4*tid..4*tid+3 per thread as f2 pairs.
// s0/g/P computed in-kernel (one extra block reduce); rcp/rsq fast math;
// src loops unrolled (dead numerator chains for c==src constant-fold).
// ---------------------------------------------------------------------------
__global__ __launch_bounds__(256) void k_main(const float* __restrict__ Xr,
                                              const float* __restrict__ Xi,
                                              float* __restrict__ out, int nout) {
  const int blk = blockIdx.x;
  const int b = blk / NF, f = blk % NF;
  const int tid = threadIdx.x;
  const int lane = tid & 63, wvid = tid >> 6;
  const float invN = 1.f / (float)NFR;

  __shared__ float red[2][4][12];
  __shared__ float Wre[NC][NC], Wim[NC][NC];
  __shared__ float abc[8];

  f2 xcr[NC][2], xci[NC][2];
  int rowbase[NC];
#pragma unroll
  for (int c = 0; c < NC; ++c) {
    rowbase[c] = ((b * NC + c) * NF + f) * NFR;
    float4 ar = reinterpret_cast<const float4*>(Xr + rowbase[c])[tid];
    float4 ai = reinterpret_cast<const float4*>(Xi + rowbase[c])[tid];
    xcr[c][0] = {ar.x, ar.y}; xcr[c][1] = {ar.z, ar.w};
    xci[c][0] = {ai.x, ai.y}; xci[c][1] = {ai.z, ai.w};
  }
  if (tid < 16) {
    Wre[tid >> 2][tid & 3] = ((tid >> 2) == (tid & 3)) ? 1.f : 0.f;
    Wim[tid >> 2][tid & 3] = 0.f;
  }

  // ---- s0[c] = mean |X|^2 over (F,N): block reduce of g_S rows (once) ----
  float s0[NC];
  {
    float q[NC];
#pragma unroll
    for (int c = 0; c < NC; ++c) {
      float4 Sv = reinterpret_cast<const float4*>(g_S + (b * NC + c) * NFR)[tid];
      q[c] = dpp_red_sum(Sv.x + Sv.y + Sv.z + Sv.w);
    }
    if (lane == 63)
      *reinterpret_cast<float4*>(&red[1][wvid][0]) = make_float4(q[0], q[1], q[2], q[3]);
    __syncthreads();
    const float invFN = 1.f / (float)(NF * NFR);
#pragma unroll
    for (int c = 0; c < NC; ++c)
      s0[c] = (red[1][0][c] + red[1][1][c] + red[1][2][c] + red[1][3][c]) * invFN;
  }

  float Pc[NC] = {1.f, 1.f, 1.f, 1.f};
  int buf = 0;

  for (int e = 0; e < 3; ++e) {
    // ---- per-epoch weights: w = g * rcp(max(2*sqrt(S/P), eps)) ----
    f2 w2[NC][2];
#pragma unroll
    for (int c = 0; c < NC; ++c) {
      float pinv = __builtin_amdgcn_rcpf(Pc[c]);
      float g = fmaxf(s0[c] * pinv, 1e-5f);
      Pc[c] *= g;
      float4 Sv = reinterpret_cast<const float4*>(g_S + (b * NC + c) * NFR)[tid];
      w2[c][0].x = g * __builtin_amdgcn_rcpf(fmaxf(2.f * __builtin_amdgcn_sqrtf(Sv.x * pinv), EPS_MODEL));
      w2[c][0].y = g * __builtin_amdgcn_rcpf(fmaxf(2.f * __builtin_amdgcn_sqrtf(Sv.y * pinv), EPS_MODEL));
      w2[c][1].x = g * __builtin_amdgcn_rcpf(fmaxf(2.f * __builtin_amdgcn_sqrtf(Sv.z * pinv), EPS_MODEL));
      w2[c][1].y = g * __builtin_amdgcn_rcpf(fmaxf(2.f * __builtin_amdgcn_sqrtf(Sv.w * pinv), EPS_MODEL));
    }

    // ================= type-1 sweeps (src unrolled -> DCE of src chains) ====
#pragma unroll
    for (int src = 0; src < NC; ++src) {
      f2 p2[12];
#pragma unroll
      for (int k = 0; k < 12; ++k) p2[k] = {0.f, 0.f};
#pragma unroll
      for (int pr = 0; pr < 2; ++pr) {
        f2 xsr = xcr[src][pr], xsi = xci[src][pr];
        f2 msq = xsr * xsr + xsi * xsi;
#pragma unroll
        for (int c = 0; c < NC; ++c) {
          f2 wv = w2[c][pr];
          if (c != src) {
            p2[c]     += wv * (xcr[c][pr] * xsr + xci[c][pr] * xsi);
            p2[4 + c] += wv * (xci[c][pr] * xsr - xcr[c][pr] * xsi);
          }
          p2[8 + c] += wv * msq;
        }
      }
      float p[12];
#pragma unroll
      for (int k = 0; k < 12; ++k) p[k] = p2[k].x + p2[k].y;
      float s12[12];
      block_reduce12(p, red, buf, lane, wvid, s12);
      buf ^= 1;

      float vr[NC], vi[NC];
#pragma unroll
      for (int c = 0; c < NC; ++c) {
        float den = fmaxf(s12[8 + c] * invN, EPSV);
        if (c == src) {
          vr[c] = 1.f - __builtin_amdgcn_rsqf(den);
          vi[c] = 0.f;
        } else {
          float sc = invN * __builtin_amdgcn_rcpf(den);
          vr[c] = s12[c] * sc;
          vi[c] = s12[4 + c] * sc;
        }
      }
#pragma unroll
      for (int pr = 0; pr < 2; ++pr) {
        f2 xsr = xcr[src][pr], xsi = xci[src][pr];
#pragma unroll
        for (int c = 0; c < NC; ++c) {
          xcr[c][pr] -= xsr * vr[c] - xsi * vi[c];
          xci[c][pr] -= xsi * vr[c] + xsr * vi[c];
        }
      }
      if (tid == 0) {
#pragma unroll
        for (int jj = 0; jj < NC; ++jj) {
          float wsr = Wre[src][jj], wsi = Wim[src][jj];
#pragma unroll
          for (int c = 0; c < NC; ++c) {
            Wre[c][jj] -= vr[c] * wsr - vi[c] * wsi;
            Wim[c][jj] -= vr[c] * wsi + vi[c] * wsr;
          }
        }
      }
    }

    // ================= type-2 sweeps =================
#pragma unroll
    for (int src = 0; src < NC; ++src) {
      const float* XrS = Xr + rowbase[src];
      const float* XiS = Xi + rowbase[src];
      // 5-frame window [4t-3 .. 4t+1] of ORIGINAL X via two float4 loads.
      float4 Ar4 = make_float4(0.f, 0.f, 0.f, 0.f), Ai4 = Ar4;
      if (tid > 0) {
        Ar4 = reinterpret_cast<const float4*>(XrS)[tid - 1];
        Ai4 = reinterpret_cast<const float4*>(XiS)[tid - 1];
      }
      float4 Br4 = reinterpret_cast<const float4*>(XrS)[tid];
      float4 Bi4 = reinterpret_cast<const float4*>(XiS)[tid];
      float wr[5] = {Ar4.y, Ar4.z, Ar4.w, Br4.x, Br4.y};
      float wi[5] = {Ai4.y, Ai4.z, Ai4.w, Bi4.x, Bi4.y};
#pragma unroll
      for (int tap = 0; tap < 2; ++tap) {
        f2 xs_r[2] = {{wr[tap], wr[tap + 1]}, {wr[tap + 2], wr[tap + 3]}};
        f2 xs_i[2] = {{wi[tap], wi[tap + 1]}, {wi[tap + 2], wi[tap + 3]}};
        f2 p2[12];
#pragma unroll
        for (int k = 0; k < 12; ++k) p2[k] = {0.f, 0.f};
#pragma unroll
        for (int pr = 0; pr < 2; ++pr) {
          f2 xsr = xs_r[pr], xsi = xs_i[pr];
          f2 msq = xsr * xsr + xsi * xsi;
#pragma unroll
          for (int c = 0; c < NC; ++c) {
            f2 wv = w2[c][pr];
            p2[c]     += wv * (xcr[c][pr] * xsr + xci[c][pr] * xsi);
            p2[4 + c] += wv * (xci[c][pr] * xsr - xcr[c][pr] * xsi);
            p2[8 + c] += wv * msq;
          }
        }
        float p[12];
#pragma unroll
        for (int k = 0; k < 12; ++k) p[k] = p2[k].x + p2[k].y;
        float s12[12];
        block_reduce12(p, red, buf, lane, wvid, s12);
        buf ^= 1;

        float vr[NC], vi[NC];
#pragma unroll
        for (int c = 0; c < NC; ++c) {
          float den = fmaxf(s12[8 + c], EPSV);  // SUM, not mean
          float sc = invN * __builtin_amdgcn_rcpf(den);
          vr[c] = s12[c] * sc;
          vi[c] = s12[4 + c] * sc;
        }
#pragma unroll
        for (int pr = 0; pr < 2; ++pr) {
          f2 xsr = xs_r[pr], xsi = xs_i[pr];
#pragma unroll
          for (int c = 0; c < NC; ++c) {
            xcr[c][pr] -= xsr * vr[c] - xsi * vi[c];
            xci[c][pr] -= xsi * vr[c] + xsr * vi[c];
          }
        }
      }
    }
  }  // epochs

  // ---- solve W^T a = e1 (4x4 complex, partial pivoting), A[i][j] = W[j][i] ----
  __syncthreads();
  if (tid == 0) {
    float Ar[4][4], Ai[4][4];
    float br[4] = {1.f, 0.f, 0.f, 0.f}, bi[4] = {0.f, 0.f, 0.f, 0.f};
#pragma unroll
    for (int i = 0; i < 4; ++i)
#pragma unroll
      for (int j = 0; j < 4; ++j) {
        Ar[i][j] = Wre[j][i];
        Ai[i][j] = Wim[j][i];
      }
    for (int k = 0; k < 4; ++k) {
      int piv = k;
      float best = Ar[k][k] * Ar[k][k] + Ai[k][k] * Ai[k][k];
      for (int i = k + 1; i < 4; ++i) {
        float m = Ar[i][k] * Ar[i][k] + Ai[i][k] * Ai[i][k];
        if (m > best) { best = m; piv = i; }
      }
      if (piv != k) {
        for (int j = 0; j < 4; ++j) {
          float t = Ar[k][j]; Ar[k][j] = Ar[piv][j]; Ar[piv][j] = t;
          t = Ai[k][j]; Ai[k][j] = Ai[piv][j]; Ai[piv][j] = t;
        }
        float t = br[k]; br[k] = br[piv]; br[piv] = t;
        t = bi[k]; bi[k] = bi[piv]; bi[piv] = t;
      }
      float dr = Ar[k][k], di = Ai[k][k];
      float inv = 1.f / (dr * dr + di * di);
      for (int i = k + 1; i < 4; ++i) {
        float fr = (Ar[i][k] * dr + Ai[i][k] * di) * inv;
        float fi = (Ai[i][k] * dr - Ar[i][k] * di) * inv;
        for (int j = k; j < 4; ++j) {
          Ar[i][j] -= fr * Ar[k][j] - fi * Ai[k][j];
          Ai[i][j] -= fr * Ai[k][j] + fi * Ar[k][j];
        }
        br[i] -= fr * br[k] - fi * bi[k];
        bi[i] -= fr * bi[k] + fi * br[k];
      }
    }
    float ar[4], ai[4];
    for (int k = 3; k >= 0; --k) {
      float sr = br[k], si = bi[k];
      for (int j = k + 1; j < 4; ++j) {
        sr -= Ar[k][j] * ar[j] - Ai[k][j] * ai[j];
        si -= Ar[k][j] * ai[j] + Ai[k][j] * ar[j];
      }
      float dr = Ar[k][k], di = Ai[k][k];
      float inv = 1.f / (dr * dr + di * di);
      ar[k] = (sr * dr + si * di) * inv;
      ai[k] = (si * dr - sr * di) * inv;
    }
#pragma unroll
    for (int c = 0; c < 4; ++c) { abc[c] = ar[c]; abc[4 + c] = ai[c]; }
  }
  __syncthreads();

  // ---- output: real(Xc * a), float4 per (c, thread), bounds-guarded ----
#pragma unroll
  for (int c = 0; c < NC; ++c) {
    float ar = abc[c], ai2 = abc[4 + c];
    if (rowbase[c] + 4 * tid + 3 < nout) {
      float4 o;
      o.x = xcr[c][0].x * ar - xci[c][0].x * ai2;
      o.y = xcr[c][0].y * ar - xci[c][0].y * ai2;
      o.z = xcr[c][1].x * ar - xci[c][1].x * ai2;
      o.w = xcr[c][1].y * ar - xci[c][1].y * ai2;
      reinterpret_cast<float4*>(out + rowbase[c])[tid] = o;
    }
  }
}

// ---------------------------------------------------------------------------
extern "C" void kernel_launch(void* const* d_in, const int* in_sizes, int n_in,
                              void* d_out, int out_size, void* d_ws, size_t ws_size,
                              hipStream_t stream) {
  const float* Xr = (const float*)d_in[0];
  const float* Xi = (const float*)d_in[1];
  float* out = (float*)d_out;

  dim3 g1(16, NCHUNK);
  k_colsum<<<g1, 256, 0, stream>>>(Xr, Xi);
  k_red<<<16, 256, 0, stream>>>();
  k_main<<<NB * NF, 256, 0, stream>>>(Xr, Xi, out, out_size);
}

// Round 7
// 224.785 us; speedup vs baseline: 1.3659x; 1.3659x over previous
//
#include <hip/hip_runtime.h>
#include <math.h>

#define NB 4
#define NC 4
#define NF 257
#define NFR 1024
#define NTOT (NB * NC * NF * NFR)
#define NBC (NB * NC)
#define EPSV 1e-3f
#define EPS_MODEL 1e-5f
#define NCHUNK 32

// Module-scope scratch: allocated at load, graph-capture safe, fully
// rewritten every call.
__device__ float g_Spart[NCHUNK * NBC * NFR];  // partial column sums
__device__ float g_S[NBC * NFR];               // S[b,c,n] = sum_f |X[b,c,f,n]|^2
__device__ float g_gP[96];                     // g_e, P_e per (b,c), e=0..2

// Wave-wide sum via DPP (VALU pipe, no LDS traffic). Lane 63 holds the sum.
__device__ __forceinline__ float dpp_red_sum(float v) {
  v += __int_as_float(__builtin_amdgcn_update_dpp(0, __float_as_int(v), 0x111, 0xf, 0xf, true)); // row_shr:1
  v += __int_as_float(__builtin_amdgcn_update_dpp(0, __float_as_int(v), 0x112, 0xf, 0xf, true)); // row_shr:2
  v += __int_as_float(__builtin_amdgcn_update_dpp(0, __float_as_int(v), 0x114, 0xf, 0xf, true)); // row_shr:4
  v += __int_as_float(__builtin_amdgcn_update_dpp(0, __float_as_int(v), 0x118, 0xf, 0xf, true)); // row_shr:8
  v += __int_as_float(__builtin_amdgcn_update_dpp(0, __float_as_int(v), 0x142, 0xa, 0xf, true)); // row_bcast:15
  v += __int_as_float(__builtin_amdgcn_update_dpp(0, __float_as_int(v), 0x143, 0xc, 0xf, true)); // row_bcast:31
  return v;
}

// ---------------------------------------------------------------------------
// K1: partial column sums, float4-vectorized, 512 blocks (full GPU).
// grid (16, 32): x covers bc*256 quad-frames, y = freq chunk of 9.
// ---------------------------------------------------------------------------
__global__ __launch_bounds__(256) void k_colsum(const float* __restrict__ Xr,
                                                const float* __restrict__ Xi) {
  int u = blockIdx.x * 256 + threadIdx.x;  // bc*256 + q
  int fc = blockIdx.y;
  int f0 = fc * 9;
  int f1 = f0 + 9; if (f1 > NF) f1 = NF;
  int bc = u >> 8, q = u & 255;
  float4 s = make_float4(0.f, 0.f, 0.f, 0.f);
  for (int f = f0; f < f1; ++f) {
    float4 a = reinterpret_cast<const float4*>(Xr + (bc * NF + f) * NFR)[q];
    float4 b = reinterpret_cast<const float4*>(Xi + (bc * NF + f) * NFR)[q];
    s.x += a.x * a.x + b.x * b.x;
    s.y += a.y * a.y + b.y * b.y;
    s.z += a.z * a.z + b.z * b.z;
    s.w += a.w * a.w + b.w * b.w;
  }
  reinterpret_cast<float4*>(g_Spart + fc * (NBC * NFR) + bc * NFR)[q] = s;
}

// ---------------------------------------------------------------------------
// K2 (fused): reduce 32 partials -> g_S; block-reduce to s0; g_e/P_e table.
// grid 16 = one block per (b,c).
// ---------------------------------------------------------------------------
__global__ __launch_bounds__(256) void k_redgp() {
  int bc = blockIdx.x, tid = threadIdx.x;
  float4 s = make_float4(0.f, 0.f, 0.f, 0.f);
#pragma unroll
  for (int fc = 0; fc < NCHUNK; ++fc) {
    float4 a = reinterpret_cast<const float4*>(g_Spart + fc * (NBC * NFR) + bc * NFR)[tid];
    s.x += a.x; s.y += a.y; s.z += a.z; s.w += a.w;
  }
  reinterpret_cast<float4*>(g_S + bc * NFR)[tid] = s;
  float p = dpp_red_sum(s.x + s.y + s.z + s.w);
  __shared__ float r[4];
  if ((tid & 63) == 63) r[tid >> 6] = p;
  __syncthreads();
  if (tid == 0) {
    float s0 = (r[0] + r[1] + r[2] + r[3]) / (float)(NF * NFR);
    float P = 1.f;
#pragma unroll
    for (int e = 0; e < 3; ++e) {
      float g = fmaxf(s0 / P, 1e-5f);
      g_gP[e * 32 + bc] = g;
      g_gP[e * 32 + 16 + bc] = P;
      P *= g;
    }
  }
}

// Block-level reduction of 12 partials: DPP within wave, one barrier,
// b128 LDS round-trip, double-buffered by caller via `buf`.
__device__ __forceinline__ void block_reduce12(float* __restrict__ p,
                                               float (*red)[4][12], int buf,
                                               int lane, int wvid,
                                               float* __restrict__ s) {
#pragma unroll
  for (int k = 0; k < 12; ++k) p[k] = dpp_red_sum(p[k]);
  if (lane == 63) {
    float4* dst = reinterpret_cast<float4*>(&red[buf][wvid][0]);
    dst[0] = make_float4(p[0], p[1], p[2], p[3]);
    dst[1] = make_float4(p[4], p[5], p[6], p[7]);
    dst[2] = make_float4(p[8], p[9], p[10], p[11]);
  }
  __syncthreads();
  const float4* r = reinterpret_cast<const float4*>(&red[buf][0][0]);
#pragma unroll
  for (int k = 0; k < 3; ++k) {
    float4 a = r[0 + k], b = r[3 + k], c = r[6 + k], d = r[9 + k];
    s[4 * k + 0] = a.x + b.x + c.x + d.x;
    s[4 * k + 1] = a.y + b.y + c.y + d.y;
    s[4 * k + 2] = a.z + b.z + c.z + d.z;
    s[4 * k + 3] = a.w + b.w + c.w + d.w;
  }
}

// ---------------------------------------------------------------------------
// Main: one block per (b,f). Frames 4*tid..4*tid+3 per thread (float4 I/O).
// Round-5 structure (76 VGPR, 22% occ) + rcp/rsq fast-path divisions.
// ---------------------------------------------------------------------------
__global__ __launch_bounds__(256) void k_main(const float* __restrict__ Xr,
                                              const float* __restrict__ Xi,
                                              float* __restrict__ out, int nout) {
  const int blk = blockIdx.x;
  const int b = blk / NF, f = blk % NF;
  const int tid = threadIdx.x;
  const int lane = tid & 63, wvid = tid >> 6;
  const float invN = 1.f / (float)NFR;

  __shared__ float red[2][4][12];
  __shared__ float Wre[NC][NC], Wim[NC][NC];
  __shared__ float abc[8];

  float xcr[NC][4], xci[NC][4];
  int rowbase[NC];
#pragma unroll
  for (int c = 0; c < NC; ++c) {
    rowbase[c] = ((b * NC + c) * NF + f) * NFR;
    float4 ar = reinterpret_cast<const float4*>(Xr + rowbase[c])[tid];
    float4 ai = reinterpret_cast<const float4*>(Xi + rowbase[c])[tid];
    xcr[c][0] = ar.x; xcr[c][1] = ar.y; xcr[c][2] = ar.z; xcr[c][3] = ar.w;
    xci[c][0] = ai.x; xci[c][1] = ai.y; xci[c][2] = ai.z; xci[c][3] = ai.w;
  }
  if (tid < 16) {
    Wre[tid >> 2][tid & 3] = ((tid >> 2) == (tid & 3)) ? 1.f : 0.f;
    Wim[tid >> 2][tid & 3] = 0.f;
  }
  // W-init visibility to thread 0: ordered by the first sweep's barrier.

  float w[NC][4];
  int buf = 0;

  for (int e = 0; e < 3; ++e) {
    // ---- per-epoch weights: w = g * rcp(max(2*sqrt(S/P), eps)) ----
#pragma unroll
    for (int c = 0; c < NC; ++c) {
      float g = g_gP[e * 32 + b * NC + c];
      float P = g_gP[e * 32 + 16 + b * NC + c];
      float sc = __builtin_amdgcn_rcpf(P);
      float4 Sv = reinterpret_cast<const float4*>(g_S + (b * NC + c) * NFR)[tid];
      w[c][0] = g * __builtin_amdgcn_rcpf(fmaxf(2.f * __builtin_amdgcn_sqrtf(Sv.x * sc), EPS_MODEL));
      w[c][1] = g * __builtin_amdgcn_rcpf(fmaxf(2.f * __builtin_amdgcn_sqrtf(Sv.y * sc), EPS_MODEL));
      w[c][2] = g * __builtin_amdgcn_rcpf(fmaxf(2.f * __builtin_amdgcn_sqrtf(Sv.z * sc), EPS_MODEL));
      w[c][3] = g * __builtin_amdgcn_rcpf(fmaxf(2.f * __builtin_amdgcn_sqrtf(Sv.w * sc), EPS_MODEL));
    }

    // ================= type-1 sweeps =================
    for (int src = 0; src < NC; ++src) {
      float p[12];
#pragma unroll
      for (int k = 0; k < 12; ++k) p[k] = 0.f;
#pragma unroll
      for (int j = 0; j < 4; ++j) {
        float xsr = xcr[src][j], xsi = xci[src][j];
        float msq = xsr * xsr + xsi * xsi;
#pragma unroll
        for (int c = 0; c < NC; ++c) {
          float wvv = w[c][j];
          p[c]     += wvv * (xcr[c][j] * xsr + xci[c][j] * xsi);
          p[4 + c] += wvv * (xci[c][j] * xsr - xcr[c][j] * xsi);
          p[8 + c] += wvv * msq;
        }
      }
      float s12[12];
      block_reduce12(p, red, buf, lane, wvid, s12);
      buf ^= 1;

      float vr[NC], vi[NC];
#pragma unroll
      for (int c = 0; c < NC; ++c) {
        float den = fmaxf(s12[8 + c] * invN, EPSV);
        if (c == src) {
          vr[c] = 1.f - __builtin_amdgcn_rsqf(den);
          vi[c] = 0.f;
        } else {
          float sc = invN * __builtin_amdgcn_rcpf(den);
          vr[c] = s12[c] * sc;
          vi[c] = s12[4 + c] * sc;
        }
      }
#pragma unroll
      for (int j = 0; j < 4; ++j) {
        float xsr = xcr[src][j], xsi = xci[src][j];
#pragma unroll
        for (int c = 0; c < NC; ++c) {
          xcr[c][j] -= vr[c] * xsr - vi[c] * xsi;
          xci[c][j] -= vr[c] * xsi + vi[c] * xsr;
        }
      }
      if (tid == 0) {
#pragma unroll
        for (int jj = 0; jj < NC; ++jj) {
          float wsr = Wre[src][jj], wsi = Wim[src][jj];
#pragma unroll
          for (int c = 0; c < NC; ++c) {
            Wre[c][jj] -= vr[c] * wsr - vi[c] * wsi;
            Wim[c][jj] -= vr[c] * wsi + vi[c] * wsr;
          }
        }
      }
    }

    // ================= type-2 sweeps =================
    for (int src = 0; src < NC; ++src) {
      const int sbase = ((b * NC + src) * NF + f) * NFR;
      // Shared 5-frame window [4t-3 .. 4t+1] of ORIGINAL X serves both taps.
      float wr[5], wi[5];
#pragma unroll
      for (int k = 0; k < 5; ++k) {
        int m = 4 * tid - 3 + k;
        bool ok = (m >= 0);
        wr[k] = ok ? Xr[sbase + m] : 0.f;
        wi[k] = ok ? Xi[sbase + m] : 0.f;
      }
      for (int tap = 0; tap < 2; ++tap) {
        float p[12];
#pragma unroll
        for (int k = 0; k < 12; ++k) p[k] = 0.f;
#pragma unroll
        for (int j = 0; j < 4; ++j) {
          float xsr = wr[j + tap], xsi = wi[j + tap];  // frame 4t+j-3+tap
          float msq = xsr * xsr + xsi * xsi;
#pragma unroll
          for (int c = 0; c < NC; ++c) {
            float wvv = w[c][j];
            p[c]     += wvv * (xcr[c][j] * xsr + xci[c][j] * xsi);
            p[4 + c] += wvv * (xci[c][j] * xsr - xcr[c][j] * xsi);
            p[8 + c] += wvv * msq;
          }
        }
        float s12[12];
        block_reduce12(p, red, buf, lane, wvid, s12);
        buf ^= 1;

        float vr[NC], vi[NC];
#pragma unroll
        for (int c = 0; c < NC; ++c) {
          float den = fmaxf(s12[8 + c], EPSV);  // SUM, not mean
          float sc = invN * __builtin_amdgcn_rcpf(den);
          vr[c] = s12[c] * sc;
          vi[c] = s12[4 + c] * sc;
        }
#pragma unroll
        for (int j = 0; j < 4; ++j) {
          float xsr = wr[j + tap], xsi = wi[j + tap];
#pragma unroll
          for (int c = 0; c < NC; ++c) {
            xcr[c][j] -= vr[c] * xsr - vi[c] * xsi;
            xci[c][j] -= vr[c] * xsi + vi[c] * xsr;
          }
        }
      }
    }
  }  // epochs

  // ---- solve W^T a = e1 (4x4 complex, partial pivoting), A[i][j] = W[j][i] ----
  __syncthreads();
  if (tid == 0) {
    float Ar[4][4], Ai[4][4];
    float br[4] = {1.f, 0.f, 0.f, 0.f}, bi[4] = {0.f, 0.f, 0.f, 0.f};
#pragma unroll
    for (int i = 0; i < 4; ++i)
#pragma unroll
      for (int j = 0; j < 4; ++j) {
        Ar[i][j] = Wre[j][i];
        Ai[i][j] = Wim[j][i];
      }
    for (int k = 0; k < 4; ++k) {
      int piv = k;
      float best = Ar[k][k] * Ar[k][k] + Ai[k][k] * Ai[k][k];
      for (int i = k + 1; i < 4; ++i) {
        float m = Ar[i][k] * Ar[i][k] + Ai[i][k] * Ai[i][k];
        if (m > best) { best = m; piv = i; }
      }
      if (piv != k) {
        for (int j = 0; j < 4; ++j) {
          float t = Ar[k][j]; Ar[k][j] = Ar[piv][j]; Ar[piv][j] = t;
          t = Ai[k][j]; Ai[k][j] = Ai[piv][j]; Ai[piv][j] = t;
        }
        float t = br[k]; br[k] = br[piv]; br[piv] = t;
        t = bi[k]; bi[k] = bi[piv]; bi[piv] = t;
      }
      float dr = Ar[k][k], di = Ai[k][k];
      float inv = 1.f / (dr * dr + di * di);
      for (int i = k + 1; i < 4; ++i) {
        float fr = (Ar[i][k] * dr + Ai[i][k] * di) * inv;
        float fi = (Ai[i][k] * dr - Ar[i][k] * di) * inv;
        for (int j = k; j < 4; ++j) {
          Ar[i][j] -= fr * Ar[k][j] - fi * Ai[k][j];
          Ai[i][j] -= fr * Ai[k][j] + fi * Ar[k][j];
        }
        br[i] -= fr * br[k] - fi * bi[k];
        bi[i] -= fr * bi[k] + fi * br[k];
      }
    }
    float ar[4], ai[4];
    for (int k = 3; k >= 0; --k) {
      float sr = br[k], si = bi[k];
      for (int j = k + 1; j < 4; ++j) {
        sr -= Ar[k][j] * ar[j] - Ai[k][j] * ai[j];
        si -= Ar[k][j] * ai[j] + Ai[k][j] * ar[j];
      }
      float dr = Ar[k][k], di = Ai[k][k];
      float inv = 1.f / (dr * dr + di * di);
      ar[k] = (sr * dr + si * di) * inv;
      ai[k] = (si * dr - sr * di) * inv;
    }
#pragma unroll
    for (int c = 0; c < 4; ++c) { abc[c] = ar[c]; abc[4 + c] = ai[c]; }
  }
  __syncthreads();

  // ---- output: real(Xc * a), float4 per (c, thread), bounds-guarded ----
#pragma unroll
  for (int c = 0; c < NC; ++c) {
    float ar = abc[c], ai2 = abc[4 + c];
    if (rowbase[c] + 4 * tid + 3 < nout) {
      float4 o;
      o.x = xcr[c][0] * ar - xci[c][0] * ai2;
      o.y = xcr[c][1] * ar - xci[c][1] * ai2;
      o.z = xcr[c][2] * ar - xci[c][2] * ai2;
      o.w = xcr[c][3] * ar - xci[c][3] * ai2;
      reinterpret_cast<float4*>(out + rowbase[c])[tid] = o;
    }
  }
}

// ---------------------------------------------------------------------------
extern "C" void kernel_launch(void* const* d_in, const int* in_sizes, int n_in,
                              void* d_out, int out_size, void* d_ws, size_t ws_size,
                              hipStream_t stream) {
  const float* Xr = (const float*)d_in[0];
  const float* Xi = (const float*)d_in[1];
  float* out = (float*)d_out;

  dim3 g1(16, NCHUNK);
  k_colsum<<<g1, 256, 0, stream>>>(Xr, Xi);
  k_redgp<<<16, 256, 0, stream>>>();
  k_main<<<NB * NF, 256, 0, stream>>>(Xr, Xi, out, out_size);
}

// Round 8
// 220.439 us; speedup vs baseline: 1.3928x; 1.0197x over previous
//
#include <hip/hip_runtime.h>
#include <math.h>

#define NB 4
#define NC 4
#define NF 257
#define NFR 1024
#define NTOT (NB * NC * NF * NFR)
#define NBC (NB * NC)
#define EPSV 1e-3f
#define EPS_MODEL 1e-5f
#define NCHUNK 32

// Module-scope scratch: allocated at load, graph-capture safe, fully
// rewritten every call.
__device__ float g_Spart[NCHUNK * NBC * NFR];  // partial column sums
__device__ float g_S[NBC * NFR];               // S[b,c,n] = sum_f |X[b,c,f,n]|^2
__device__ float g_gP[96];                     // g_e, P_e per (b,c), e=0..2

// Wave-wide sum via DPP (VALU pipe, no LDS traffic). Lane 63 holds the sum.
__device__ __forceinline__ float dpp_red_sum(float v) {
  v += __int_as_float(__builtin_amdgcn_update_dpp(0, __float_as_int(v), 0x111, 0xf, 0xf, true)); // row_shr:1
  v += __int_as_float(__builtin_amdgcn_update_dpp(0, __float_as_int(v), 0x112, 0xf, 0xf, true)); // row_shr:2
  v += __int_as_float(__builtin_amdgcn_update_dpp(0, __float_as_int(v), 0x114, 0xf, 0xf, true)); // row_shr:4
  v += __int_as_float(__builtin_amdgcn_update_dpp(0, __float_as_int(v), 0x118, 0xf, 0xf, true)); // row_shr:8
  v += __int_as_float(__builtin_amdgcn_update_dpp(0, __float_as_int(v), 0x142, 0xa, 0xf, true)); // row_bcast:15
  v += __int_as_float(__builtin_amdgcn_update_dpp(0, __float_as_int(v), 0x143, 0xc, 0xf, true)); // row_bcast:31
  return v;
}

// ---------------------------------------------------------------------------
// K1: partial column sums, float4-vectorized, 512 blocks (full GPU).
// ---------------------------------------------------------------------------
__global__ __launch_bounds__(256) void k_colsum(const float* __restrict__ Xr,
                                                const float* __restrict__ Xi) {
  int u = blockIdx.x * 256 + threadIdx.x;  // bc*256 + q
  int fc = blockIdx.y;
  int f0 = fc * 9;
  int f1 = f0 + 9; if (f1 > NF) f1 = NF;
  int bc = u >> 8, q = u & 255;
  float4 s = make_float4(0.f, 0.f, 0.f, 0.f);
  for (int f = f0; f < f1; ++f) {
    float4 a = reinterpret_cast<const float4*>(Xr + (bc * NF + f) * NFR)[q];
    float4 b = reinterpret_cast<const float4*>(Xi + (bc * NF + f) * NFR)[q];
    s.x += a.x * a.x + b.x * b.x;
    s.y += a.y * a.y + b.y * b.y;
    s.z += a.z * a.z + b.z * b.z;
    s.w += a.w * a.w + b.w * b.w;
  }
  reinterpret_cast<float4*>(g_Spart + fc * (NBC * NFR) + bc * NFR)[q] = s;
}

// ---------------------------------------------------------------------------
// K2 (fused): reduce 32 partials -> g_S; block-reduce to s0; g_e/P_e table.
// ---------------------------------------------------------------------------
__global__ __launch_bounds__(256) void k_redgp() {
  int bc = blockIdx.x, tid = threadIdx.x;
  float4 s = make_float4(0.f, 0.f, 0.f, 0.f);
#pragma unroll
  for (int fc = 0; fc < NCHUNK; ++fc) {
    float4 a = reinterpret_cast<const float4*>(g_Spart + fc * (NBC * NFR) + bc * NFR)[tid];
    s.x += a.x; s.y += a.y; s.z += a.z; s.w += a.w;
  }
  reinterpret_cast<float4*>(g_S + bc * NFR)[tid] = s;
  float p = dpp_red_sum(s.x + s.y + s.z + s.w);
  __shared__ float r[4];
  if ((tid & 63) == 63) r[tid >> 6] = p;
  __syncthreads();
  if (tid == 0) {
    float s0 = (r[0] + r[1] + r[2] + r[3]) / (float)(NF * NFR);
    float P = 1.f;
#pragma unroll
    for (int e = 0; e < 3; ++e) {
      float g = fmaxf(s0 / P, 1e-5f);
      g_gP[e * 32 + bc] = g;
      g_gP[e * 32 + 16 + bc] = P;
      P *= g;
    }
  }
}

// Block-level reduction of 12 partials, 2-wave version: DPP within wave,
// one barrier, b128 LDS round-trip, double-buffered via `buf`.
__device__ __forceinline__ void block_reduce12(float* __restrict__ p,
                                               float (*red)[2][12], int buf,
                                               int lane, int wvid,
                                               float* __restrict__ s) {
#pragma unroll
  for (int k = 0; k < 12; ++k) p[k] = dpp_red_sum(p[k]);
  if (lane == 63) {
    float4* dst = reinterpret_cast<float4*>(&red[buf][wvid][0]);
    dst[0] = make_float4(p[0], p[1], p[2], p[3]);
    dst[1] = make_float4(p[4], p[5], p[6], p[7]);
    dst[2] = make_float4(p[8], p[9], p[10], p[11]);
  }
  __syncthreads();
  const float4* r = reinterpret_cast<const float4*>(&red[buf][0][0]);
#pragma unroll
  for (int k = 0; k < 3; ++k) {
    float4 a = r[k], b = r[3 + k];
    s[4 * k + 0] = a.x + b.x;
    s[4 * k + 1] = a.y + b.y;
    s[4 * k + 2] = a.z + b.z;
    s[4 * k + 3] = a.w + b.w;
  }
}

// ---------------------------------------------------------------------------
// Main: one block per (b,f), 128 threads (2 waves), 8 frames/thread.
// Halved DPP/combine/barrier overhead vs 4-wave version; <=168 VGPR target
// so 6 blocks/CU -> all 1028 blocks co-resident (no cohort tail).
// ---------------------------------------------------------------------------
__global__ __launch_bounds__(128, 3) void k_main(const float* __restrict__ Xr,
                                                 const float* __restrict__ Xi,
                                                 float* __restrict__ out, int nout) {
  const int blk = blockIdx.x;
  const int b = blk / NF, f = blk % NF;
  const int tid = threadIdx.x;            // 0..127
  const int lane = tid & 63, wvid = tid >> 6;
  const float invN = 1.f / (float)NFR;

  __shared__ float red[2][2][12];
  __shared__ float Wre[NC][NC], Wim[NC][NC];
  __shared__ float abc[8];

  float xcr[NC][8], xci[NC][8];
  int rowbase[NC];
#pragma unroll
  for (int c = 0; c < NC; ++c) {
    rowbase[c] = ((b * NC + c) * NF + f) * NFR;
    const float4* pr = reinterpret_cast<const float4*>(Xr + rowbase[c]);
    const float4* pi = reinterpret_cast<const float4*>(Xi + rowbase[c]);
    float4 a0 = pr[2 * tid], a1 = pr[2 * tid + 1];
    float4 b0 = pi[2 * tid], b1 = pi[2 * tid + 1];
    xcr[c][0] = a0.x; xcr[c][1] = a0.y; xcr[c][2] = a0.z; xcr[c][3] = a0.w;
    xcr[c][4] = a1.x; xcr[c][5] = a1.y; xcr[c][6] = a1.z; xcr[c][7] = a1.w;
    xci[c][0] = b0.x; xci[c][1] = b0.y; xci[c][2] = b0.z; xci[c][3] = b0.w;
    xci[c][4] = b1.x; xci[c][5] = b1.y; xci[c][6] = b1.z; xci[c][7] = b1.w;
  }
  if (tid < 16) {
    Wre[tid >> 2][tid & 3] = ((tid >> 2) == (tid & 3)) ? 1.f : 0.f;
    Wim[tid >> 2][tid & 3] = 0.f;
  }
  // W-init visibility to thread 0: ordered by the first sweep's barrier.

  float w[NC][8];
  int buf = 0;

  for (int e = 0; e < 3; ++e) {
    // ---- per-epoch weights: w = g * rcp(max(2*sqrt(S/P), eps)) ----
#pragma unroll
    for (int c = 0; c < NC; ++c) {
      float g = g_gP[e * 32 + b * NC + c];
      float P = g_gP[e * 32 + 16 + b * NC + c];
      float sc = __builtin_amdgcn_rcpf(P);
      const float4* ps = reinterpret_cast<const float4*>(g_S + (b * NC + c) * NFR);
      float4 S0 = ps[2 * tid], S1 = ps[2 * tid + 1];
      float sv[8] = {S0.x, S0.y, S0.z, S0.w, S1.x, S1.y, S1.z, S1.w};
#pragma unroll
      for (int j = 0; j < 8; ++j)
        w[c][j] = g * __builtin_amdgcn_rcpf(fmaxf(2.f * __builtin_amdgcn_sqrtf(sv[j] * sc), EPS_MODEL));
    }

    // ================= type-1 sweeps =================
    for (int src = 0; src < NC; ++src) {
      float p[12];
#pragma unroll
      for (int k = 0; k < 12; ++k) p[k] = 0.f;
#pragma unroll
      for (int j = 0; j < 8; ++j) {
        float xsr = xcr[src][j], xsi = xci[src][j];
        float msq = xsr * xsr + xsi * xsi;
#pragma unroll
        for (int c = 0; c < NC; ++c) {
          float wvv = w[c][j];
          p[c]     += wvv * (xcr[c][j] * xsr + xci[c][j] * xsi);
          p[4 + c] += wvv * (xci[c][j] * xsr - xcr[c][j] * xsi);
          p[8 + c] += wvv * msq;
        }
      }
      float s12[12];
      block_reduce12(p, red, buf, lane, wvid, s12);
      buf ^= 1;

      float vr[NC], vi[NC];
#pragma unroll
      for (int c = 0; c < NC; ++c) {
        float den = fmaxf(s12[8 + c] * invN, EPSV);
        if (c == src) {
          vr[c] = 1.f - __builtin_amdgcn_rsqf(den);
          vi[c] = 0.f;
        } else {
          float sc = invN * __builtin_amdgcn_rcpf(den);
          vr[c] = s12[c] * sc;
          vi[c] = s12[4 + c] * sc;
        }
      }
#pragma unroll
      for (int j = 0; j < 8; ++j) {
        float xsr = xcr[src][j], xsi = xci[src][j];
#pragma unroll
        for (int c = 0; c < NC; ++c) {
          xcr[c][j] -= vr[c] * xsr - vi[c] * xsi;
          xci[c][j] -= vr[c] * xsi + vi[c] * xsr;
        }
      }
      if (tid == 0) {
#pragma unroll
        for (int jj = 0; jj < NC; ++jj) {
          float wsr = Wre[src][jj], wsi = Wim[src][jj];
#pragma unroll
          for (int c = 0; c < NC; ++c) {
            Wre[c][jj] -= vr[c] * wsr - vi[c] * wsi;
            Wim[c][jj] -= vr[c] * wsi + vi[c] * wsr;
          }
        }
      }
    }

    // ================= type-2 sweeps =================
    for (int src = 0; src < NC; ++src) {
      const float4* pr = reinterpret_cast<const float4*>(Xr + rowbase[src]);
      const float4* pi = reinterpret_cast<const float4*>(Xi + rowbase[src]);
      // 9-frame window [8t-3 .. 8t+5] of ORIGINAL X serves both taps.
      float4 A4r = make_float4(0.f, 0.f, 0.f, 0.f), A4i = A4r;
      if (tid > 0) { A4r = pr[2 * tid - 1]; A4i = pi[2 * tid - 1]; }
      float4 B4r = pr[2 * tid], B4i = pi[2 * tid];
      float4 C4r = pr[2 * tid + 1], C4i = pi[2 * tid + 1];
      float wr[9] = {A4r.y, A4r.z, A4r.w, B4r.x, B4r.y, B4r.z, B4r.w, C4r.x, C4r.y};
      float wi[9] = {A4i.y, A4i.z, A4i.w, B4i.x, B4i.y, B4i.z, B4i.w, C4i.x, C4i.y};
      for (int tap = 0; tap < 2; ++tap) {
        float p[12];
#pragma unroll
        for (int k = 0; k < 12; ++k) p[k] = 0.f;
#pragma unroll
        for (int j = 0; j < 8; ++j) {
          float xsr = wr[j + tap], xsi = wi[j + tap];  // frame 8t+j-3+tap
          float msq = xsr * xsr + xsi * xsi;
#pragma unroll
          for (int c = 0; c < NC; ++c) {
            float wvv = w[c][j];
            p[c]     += wvv * (xcr[c][j] * xsr + xci[c][j] * xsi);
            p[4 + c] += wvv * (xci[c][j] * xsr - xcr[c][j] * xsi);
            p[8 + c] += wvv * msq;
          }
        }
        float s12[12];
        block_reduce12(p, red, buf, lane, wvid, s12);
        buf ^= 1;

        float vr[NC], vi[NC];
#pragma unroll
        for (int c = 0; c < NC; ++c) {
          float den = fmaxf(s12[8 + c], EPSV);  // SUM, not mean
          float sc = invN * __builtin_amdgcn_rcpf(den);
          vr[c] = s12[c] * sc;
          vi[c] = s12[4 + c] * sc;
        }
#pragma unroll
        for (int j = 0; j < 8; ++j) {
          float xsr = wr[j + tap], xsi = wi[j + tap];
#pragma unroll
          for (int c = 0; c < NC; ++c) {
            xcr[c][j] -= vr[c] * xsr - vi[c] * xsi;
            xci[c][j] -= vr[c] * xsi + vi[c] * xsr;
          }
        }
      }
    }
  }  // epochs

  // ---- solve W^T a = e1 (4x4 complex, partial pivoting), A[i][j] = W[j][i] ----
  __syncthreads();
  if (tid == 0) {
    float Ar[4][4], Ai[4][4];
    float br[4] = {1.f, 0.f, 0.f, 0.f}, bi[4] = {0.f, 0.f, 0.f, 0.f};
#pragma unroll
    for (int i = 0; i < 4; ++i)
#pragma unroll
      for (int j = 0; j < 4; ++j) {
        Ar[i][j] = Wre[j][i];
        Ai[i][j] = Wim[j][i];
      }
    for (int k = 0; k < 4; ++k) {
      int piv = k;
      float best = Ar[k][k] * Ar[k][k] + Ai[k][k] * Ai[k][k];
      for (int i = k + 1; i < 4; ++i) {
        float m = Ar[i][k] * Ar[i][k] + Ai[i][k] * Ai[i][k];
        if (m > best) { best = m; piv = i; }
      }
      if (piv != k) {
        for (int j = 0; j < 4; ++j) {
          float t = Ar[k][j]; Ar[k][j] = Ar[piv][j]; Ar[piv][j] = t;
          t = Ai[k][j]; Ai[k][j] = Ai[piv][j]; Ai[piv][j] = t;
        }
        float t = br[k]; br[k] = br[piv]; br[piv] = t;
        t = bi[k]; bi[k] = bi[piv]; bi[piv] = t;
      }
      float dr = Ar[k][k], di = Ai[k][k];
      float inv = 1.f / (dr * dr + di * di);
      for (int i = k + 1; i < 4; ++i) {
        float fr = (Ar[i][k] * dr + Ai[i][k] * di) * inv;
        float fi = (Ai[i][k] * dr - Ar[i][k] * di) * inv;
        for (int j = k; j < 4; ++j) {
          Ar[i][j] -= fr * Ar[k][j] - fi * Ai[k][j];
          Ai[i][j] -= fr * Ai[k][j] + fi * Ar[k][j];
        }
        br[i] -= fr * br[k] - fi * bi[k];
        bi[i] -= fr * bi[k] + fi * br[k];
      }
    }
    float ar[4], ai[4];
    for (int k = 3; k >= 0; --k) {
      float sr = br[k], si = bi[k];
      for (int j = k + 1; j < 4; ++j) {
        sr -= Ar[k][j] * ar[j] - Ai[k][j] * ai[j];
        si -= Ar[k][j] * ai[j] + Ai[k][j] * ar[j];
      }
      float dr = Ar[k][k], di = Ai[k][k];
      float inv = 1.f / (dr * dr + di * di);
      ar[k] = (sr * dr + si * di) * inv;
      ai[k] = (si * dr - sr * di) * inv;
    }
#pragma unroll
    for (int c = 0; c < 4; ++c) { abc[c] = ar[c]; abc[4 + c] = ai[c]; }
  }
  __syncthreads();

  // ---- output: real(Xc * a), 2x float4 per (c, thread), bounds-guarded ----
#pragma unroll
  for (int c = 0; c < NC; ++c) {
    float ar = abc[c], ai2 = abc[4 + c];
    if (rowbase[c] + 8 * tid + 7 < nout) {
      float4* po = reinterpret_cast<float4*>(out + rowbase[c]);
      float4 o0, o1;
      o0.x = xcr[c][0] * ar - xci[c][0] * ai2;
      o0.y = xcr[c][1] * ar - xci[c][1] * ai2;
      o0.z = xcr[c][2] * ar - xci[c][2] * ai2;
      o0.w = xcr[c][3] * ar - xci[c][3] * ai2;
      o1.x = xcr[c][4] * ar - xci[c][4] * ai2;
      o1.y = xcr[c][5] * ar - xci[c][5] * ai2;
      o1.z = xcr[c][6] * ar - xci[c][6] * ai2;
      o1.w = xcr[c][7] * ar - xci[c][7] * ai2;
      po[2 * tid] = o0;
      po[2 * tid + 1] = o1;
    }
  }
}

// ---------------------------------------------------------------------------
extern "C" void kernel_launch(void* const* d_in, const int* in_sizes, int n_in,
                              void* d_out, int out_size, void* d_ws, size_t ws_size,
                              hipStream_t stream) {
  const float* Xr = (const float*)d_in[0];
  const float* Xi = (const float*)d_in[1];
  float* out = (float*)d_out;

  dim3 g1(16, NCHUNK);
  k_colsum<<<g1, 256, 0, stream>>>(Xr, Xi);
  k_redgp<<<16, 256, 0, stream>>>();
  k_main<<<NB * NF, 128, 0, stream>>>(Xr, Xi, out, out_size);
}

// Round 9
// 205.206 us; speedup vs baseline: 1.4962x; 1.0742x over previous
//
#include <hip/hip_runtime.h>
#include <math.h>

#define NB 4
#define NC 4
#define NF 257
#define NFR 1024
#define NTOT (NB * NC * NF * NFR)
#define NBC (NB * NC)
#define EPSV 1e-3f
#define EPS_MODEL 1e-5f
#define NCHUNK 32

// Module-scope scratch: allocated at load, graph-capture safe, fully
// rewritten every call.
__device__ float g_Spart[NCHUNK * NBC * NFR];  // partial column sums
__device__ float g_S[NBC * NFR];               // S[b,c,n] = sum_f |X[b,c,f,n]|^2
__device__ float g_gP[96];                     // g_e, P_e per (b,c), e=0..2

// Wave-wide sum via DPP (VALU pipe, no LDS traffic). Lane 63 holds the sum.
__device__ __forceinline__ float dpp_red_sum(float v) {
  v += __int_as_float(__builtin_amdgcn_update_dpp(0, __float_as_int(v), 0x111, 0xf, 0xf, true)); // row_shr:1
  v += __int_as_float(__builtin_amdgcn_update_dpp(0, __float_as_int(v), 0x112, 0xf, 0xf, true)); // row_shr:2
  v += __int_as_float(__builtin_amdgcn_update_dpp(0, __float_as_int(v), 0x114, 0xf, 0xf, true)); // row_shr:4
  v += __int_as_float(__builtin_amdgcn_update_dpp(0, __float_as_int(v), 0x118, 0xf, 0xf, true)); // row_shr:8
  v += __int_as_float(__builtin_amdgcn_update_dpp(0, __float_as_int(v), 0x142, 0xa, 0xf, true)); // row_bcast:15
  v += __int_as_float(__builtin_amdgcn_update_dpp(0, __float_as_int(v), 0x143, 0xc, 0xf, true)); // row_bcast:31
  return v;
}

// ---------------------------------------------------------------------------
// K1: partial column sums, float4-vectorized, 512 blocks (full GPU).
// ---------------------------------------------------------------------------
__global__ __launch_bounds__(256) void k_colsum(const float* __restrict__ Xr,
                                                const float* __restrict__ Xi) {
  int u = blockIdx.x * 256 + threadIdx.x;  // bc*256 + q
  int fc = blockIdx.y;
  int f0 = fc * 9;
  int f1 = f0 + 9; if (f1 > NF) f1 = NF;
  int bc = u >> 8, q = u & 255;
  float4 s = make_float4(0.f, 0.f, 0.f, 0.f);
  for (int f = f0; f < f1; ++f) {
    float4 a = reinterpret_cast<const float4*>(Xr + (bc * NF + f) * NFR)[q];
    float4 b = reinterpret_cast<const float4*>(Xi + (bc * NF + f) * NFR)[q];
    s.x += a.x * a.x + b.x * b.x;
    s.y += a.y * a.y + b.y * b.y;
    s.z += a.z * a.z + b.z * b.z;
    s.w += a.w * a.w + b.w * b.w;
  }
  reinterpret_cast<float4*>(g_Spart + fc * (NBC * NFR) + bc * NFR)[q] = s;
}

// ---------------------------------------------------------------------------
// K2 (fused): reduce 32 partials -> g_S; block-reduce to s0; g_e/P_e table.
// ---------------------------------------------------------------------------
__global__ __launch_bounds__(256) void k_redgp() {
  int bc = blockIdx.x, tid = threadIdx.x;
  float4 s = make_float4(0.f, 0.f, 0.f, 0.f);
#pragma unroll
  for (int fc = 0; fc < NCHUNK; ++fc) {
    float4 a = reinterpret_cast<const float4*>(g_Spart + fc * (NBC * NFR) + bc * NFR)[tid];
    s.x += a.x; s.y += a.y; s.z += a.z; s.w += a.w;
  }
  reinterpret_cast<float4*>(g_S + bc * NFR)[tid] = s;
  float p = dpp_red_sum(s.x + s.y + s.z + s.w);
  __shared__ float r[4];
  if ((tid & 63) == 63) r[tid >> 6] = p;
  __syncthreads();
  if (tid == 0) {
    float s0 = (r[0] + r[1] + r[2] + r[3]) / (float)(NF * NFR);
    float P = 1.f;
#pragma unroll
    for (int e = 0; e < 3; ++e) {
      float g = fmaxf(s0 / P, 1e-5f);
      g_gP[e * 32 + bc] = g;
      g_gP[e * 32 + 16 + bc] = P;
      P *= g;
    }
  }
}

// Block-level reduction of 12 partials, 2-wave version: DPP within wave,
// one barrier, b128 LDS round-trip, double-buffered via `buf`.
__device__ __forceinline__ void block_reduce12(float* __restrict__ p,
                                               float (*red)[2][12], int buf,
                                               int lane, int wvid,
                                               float* __restrict__ s) {
#pragma unroll
  for (int k = 0; k < 12; ++k) p[k] = dpp_red_sum(p[k]);
  if (lane == 63) {
    float4* dst = reinterpret_cast<float4*>(&red[buf][wvid][0]);
    dst[0] = make_float4(p[0], p[1], p[2], p[3]);
    dst[1] = make_float4(p[4], p[5], p[6], p[7]);
    dst[2] = make_float4(p[8], p[9], p[10], p[11]);
  }
  __syncthreads();
  const float4* r = reinterpret_cast<const float4*>(&red[buf][0][0]);
#pragma unroll
  for (int k = 0; k < 3; ++k) {
    float4 a = r[k], b = r[3 + k];
    s[4 * k + 0] = a.x + b.x;
    s[4 * k + 1] = a.y + b.y;
    s[4 * k + 2] = a.z + b.z;
    s[4 * k + 3] = a.w + b.w;
  }
}

// ---------------------------------------------------------------------------
// Main: one block per (b,f), 128 threads (2 waves), 8 frames/thread.
// __launch_bounds__(128, 2): VGPR cap 256 -> no spills (round 8's (128,3)
// capped at ~85 VGPR and spilled ~105 MB to scratch). Actual ~150-170 VGPR
// gives 3 waves/EU (6 blocks/CU) naturally -> all 1028 blocks co-resident.
// ---------------------------------------------------------------------------
__global__ __launch_bounds__(128, 2) void k_main(const float* __restrict__ Xr,
                                                 const float* __restrict__ Xi,
                                                 float* __restrict__ out, int nout) {
  const int blk = blockIdx.x;
  const int b = blk / NF, f = blk % NF;
  const int tid = threadIdx.x;            // 0..127
  const int lane = tid & 63, wvid = tid >> 6;
  const float invN = 1.f / (float)NFR;

  __shared__ float red[2][2][12];
  __shared__ float Wre[NC][NC], Wim[NC][NC];
  __shared__ float abc[8];

  float xcr[NC][8], xci[NC][8];
  int rowbase[NC];
#pragma unroll
  for (int c = 0; c < NC; ++c) {
    rowbase[c] = ((b * NC + c) * NF + f) * NFR;
    const float4* pr = reinterpret_cast<const float4*>(Xr + rowbase[c]);
    const float4* pi = reinterpret_cast<const float4*>(Xi + rowbase[c]);
    float4 a0 = pr[2 * tid], a1 = pr[2 * tid + 1];
    float4 b0 = pi[2 * tid], b1 = pi[2 * tid + 1];
    xcr[c][0] = a0.x; xcr[c][1] = a0.y; xcr[c][2] = a0.z; xcr[c][3] = a0.w;
    xcr[c][4] = a1.x; xcr[c][5] = a1.y; xcr[c][6] = a1.z; xcr[c][7] = a1.w;
    xci[c][0] = b0.x; xci[c][1] = b0.y; xci[c][2] = b0.z; xci[c][3] = b0.w;
    xci[c][4] = b1.x; xci[c][5] = b1.y; xci[c][6] = b1.z; xci[c][7] = b1.w;
  }
  if (tid < 16) {
    Wre[tid >> 2][tid & 3] = ((tid >> 2) == (tid & 3)) ? 1.f : 0.f;
    Wim[tid >> 2][tid & 3] = 0.f;
  }
  // W-init visibility to thread 0: ordered by the first sweep's barrier.

  float w[NC][8];
  int buf = 0;

  for (int e = 0; e < 3; ++e) {
    // ---- per-epoch weights: w = g * rcp(max(2*sqrt(S/P), eps)) ----
#pragma unroll
    for (int c = 0; c < NC; ++c) {
      float g = g_gP[e * 32 + b * NC + c];
      float P = g_gP[e * 32 + 16 + b * NC + c];
      float sc = __builtin_amdgcn_rcpf(P);
      const float4* ps = reinterpret_cast<const float4*>(g_S + (b * NC + c) * NFR);
      float4 S0 = ps[2 * tid], S1 = ps[2 * tid + 1];
      float sv[8] = {S0.x, S0.y, S0.z, S0.w, S1.x, S1.y, S1.z, S1.w};
#pragma unroll
      for (int j = 0; j < 8; ++j)
        w[c][j] = g * __builtin_amdgcn_rcpf(fmaxf(2.f * __builtin_amdgcn_sqrtf(sv[j] * sc), EPS_MODEL));
    }

    // ================= type-1 sweeps =================
    for (int src = 0; src < NC; ++src) {
      float p[12];
#pragma unroll
      for (int k = 0; k < 12; ++k) p[k] = 0.f;
#pragma unroll
      for (int j = 0; j < 8; ++j) {
        float xsr = xcr[src][j], xsi = xci[src][j];
        float msq = xsr * xsr + xsi * xsi;
#pragma unroll
        for (int c = 0; c < NC; ++c) {
          float wvv = w[c][j];
          p[c]     += wvv * (xcr[c][j] * xsr + xci[c][j] * xsi);
          p[4 + c] += wvv * (xci[c][j] * xsr - xcr[c][j] * xsi);
          p[8 + c] += wvv * msq;
        }
      }
      float s12[12];
      block_reduce12(p, red, buf, lane, wvid, s12);
      buf ^= 1;

      float vr[NC], vi[NC];
#pragma unroll
      for (int c = 0; c < NC; ++c) {
        float den = fmaxf(s12[8 + c] * invN, EPSV);
        if (c == src) {
          vr[c] = 1.f - __builtin_amdgcn_rsqf(den);
          vi[c] = 0.f;
        } else {
          float sc = invN * __builtin_amdgcn_rcpf(den);
          vr[c] = s12[c] * sc;
          vi[c] = s12[4 + c] * sc;
        }
      }
#pragma unroll
      for (int j = 0; j < 8; ++j) {
        float xsr = xcr[src][j], xsi = xci[src][j];
#pragma unroll
        for (int c = 0; c < NC; ++c) {
          xcr[c][j] -= vr[c] * xsr - vi[c] * xsi;
          xci[c][j] -= vr[c] * xsi + vi[c] * xsr;
        }
      }
      if (tid == 0) {
#pragma unroll
        for (int jj = 0; jj < NC; ++jj) {
          float wsr = Wre[src][jj], wsi = Wim[src][jj];
#pragma unroll
          for (int c = 0; c < NC; ++c) {
            Wre[c][jj] -= vr[c] * wsr - vi[c] * wsi;
            Wim[c][jj] -= vr[c] * wsi + vi[c] * wsr;
          }
        }
      }
    }

    // ================= type-2 sweeps =================
    for (int src = 0; src < NC; ++src) {
      const float4* pr = reinterpret_cast<const float4*>(Xr + rowbase[src]);
      const float4* pi = reinterpret_cast<const float4*>(Xi + rowbase[src]);
      // 9-frame window [8t-3 .. 8t+5] of ORIGINAL X serves both taps.
      float4 A4r = make_float4(0.f, 0.f, 0.f, 0.f), A4i = A4r;
      if (tid > 0) { A4r = pr[2 * tid - 1]; A4i = pi[2 * tid - 1]; }
      float4 B4r = pr[2 * tid], B4i = pi[2 * tid];
      float4 C4r = pr[2 * tid + 1], C4i = pi[2 * tid + 1];
      float wr[9] = {A4r.y, A4r.z, A4r.w, B4r.x, B4r.y, B4r.z, B4r.w, C4r.x, C4r.y};
      float wi[9] = {A4i.y, A4i.z, A4i.w, B4i.x, B4i.y, B4i.z, B4i.w, C4i.x, C4i.y};
      for (int tap = 0; tap < 2; ++tap) {
        float p[12];
#pragma unroll
        for (int k = 0; k < 12; ++k) p[k] = 0.f;
#pragma unroll
        for (int j = 0; j < 8; ++j) {
          float xsr = wr[j + tap], xsi = wi[j + tap];  // frame 8t+j-3+tap
          float msq = xsr * xsr + xsi * xsi;
#pragma unroll
          for (int c = 0; c < NC; ++c) {
            float wvv = w[c][j];
            p[c]     += wvv * (xcr[c][j] * xsr + xci[c][j] * xsi);
            p[4 + c] += wvv * (xci[c][j] * xsr - xcr[c][j] * xsi);
            p[8 + c] += wvv * msq;
          }
        }
        float s12[12];
        block_reduce12(p, red, buf, lane, wvid, s12);
        buf ^= 1;

        float vr[NC], vi[NC];
#pragma unroll
        for (int c = 0; c < NC; ++c) {
          float den = fmaxf(s12[8 + c], EPSV);  // SUM, not mean
          float sc = invN * __builtin_amdgcn_rcpf(den);
          vr[c] = s12[c] * sc;
          vi[c] = s12[4 + c] * sc;
        }
#pragma unroll
        for (int j = 0; j < 8; ++j) {
          float xsr = wr[j + tap], xsi = wi[j + tap];
#pragma unroll
          for (int c = 0; c < NC; ++c) {
            xcr[c][j] -= vr[c] * xsr - vi[c] * xsi;
            xci[c][j] -= vr[c] * xsi + vi[c] * xsr;
          }
        }
      }
    }
  }  // epochs

  // ---- solve W^T a = e1 (4x4 complex, partial pivoting), A[i][j] = W[j][i] ----
  __syncthreads();
  if (tid == 0) {
    float Ar[4][4], Ai[4][4];
    float br[4] = {1.f, 0.f, 0.f, 0.f}, bi[4] = {0.f, 0.f, 0.f, 0.f};
#pragma unroll
    for (int i = 0; i < 4; ++i)
#pragma unroll
      for (int j = 0; j < 4; ++j) {
        Ar[i][j] = Wre[j][i];
        Ai[i][j] = Wim[j][i];
      }
    for (int k = 0; k < 4; ++k) {
      int piv = k;
      float best = Ar[k][k] * Ar[k][k] + Ai[k][k] * Ai[k][k];
      for (int i = k + 1; i < 4; ++i) {
        float m = Ar[i][k] * Ar[i][k] + Ai[i][k] * Ai[i][k];
        if (m > best) { best = m; piv = i; }
      }
      if (piv != k) {
        for (int j = 0; j < 4; ++j) {
          float t = Ar[k][j]; Ar[k][j] = Ar[piv][j]; Ar[piv][j] = t;
          t = Ai[k][j]; Ai[k][j] = Ai[piv][j]; Ai[piv][j] = t;
        }
        float t = br[k]; br[k] = br[piv]; br[piv] = t;
        t = bi[k]; bi[k] = bi[piv]; bi[piv] = t;
      }
      float dr = Ar[k][k], di = Ai[k][k];
      float inv = 1.f / (dr * dr + di * di);
      for (int i = k + 1; i < 4; ++i) {
        float fr = (Ar[i][k] * dr + Ai[i][k] * di) * inv;
        float fi = (Ai[i][k] * dr - Ar[i][k] * di) * inv;
        for (int j = k; j < 4; ++j) {
          Ar[i][j] -= fr * Ar[k][j] - fi * Ai[k][j];
          Ai[i][j] -= fr * Ai[k][j] + fi * Ar[k][j];
        }
        br[i] -= fr * br[k] - fi * bi[k];
        bi[i] -= fr * bi[k] + fi * br[k];
      }
    }
    float ar[4], ai[4];
    for (int k = 3; k >= 0; --k) {
      float sr = br[k], si = bi[k];
      for (int j = k + 1; j < 4; ++j) {
        sr -= Ar[k][j] * ar[j] - Ai[k][j] * ai[j];
        si -= Ar[k][j] * ai[j] + Ai[k][j] * ar[j];
      }
      float dr = Ar[k][k], di = Ai[k][k];
      float inv = 1.f / (dr * dr + di * di);
      ar[k] = (sr * dr + si * di) * inv;
      ai[k] = (si * dr - sr * di) * inv;
    }
#pragma unroll
    for (int c = 0; c < 4; ++c) { abc[c] = ar[c]; abc[4 + c] = ai[c]; }
  }
  __syncthreads();

  // ---- output: real(Xc * a), 2x float4 per (c, thread), bounds-guarded ----
#pragma unroll
  for (int c = 0; c < NC; ++c) {
    float ar = abc[c], ai2 = abc[4 + c];
    if (rowbase[c] + 8 * tid + 7 < nout) {
      float4* po = reinterpret_cast<float4*>(out + rowbase[c]);
      float4 o0, o1;
      o0.x = xcr[c][0] * ar - xci[c][0] * ai2;
      o0.y = xcr[c][1] * ar - xci[c][1] * ai2;
      o0.z = xcr[c][2] * ar - xci[c][2] * ai2;
      o0.w = xcr[c][3] * ar - xci[c][3] * ai2;
      o1.x = xcr[c][4] * ar - xci[c][4] * ai2;
      o1.y = xcr[c][5] * ar - xci[c][5] * ai2;
      o1.z = xcr[c][6] * ar - xci[c][6] * ai2;
      o1.w = xcr[c][7] * ar - xci[c][7] * ai2;
      po[2 * tid] = o0;
      po[2 * tid + 1] = o1;
    }
  }
}

// ---------------------------------------------------------------------------
extern "C" void kernel_launch(void* const* d_in, const int* in_sizes, int n_in,
                              void* d_out, int out_size, void* d_ws, size_t ws_size,
                              hipStream_t stream) {
  const float* Xr = (const float*)d_in[0];
  const float* Xi = (const float*)d_in[1];
  float* out = (float*)d_out;

  dim3 g1(16, NCHUNK);
  k_colsum<<<g1, 256, 0, stream>>>(Xr, Xi);
  k_redgp<<<16, 256, 0, stream>>>();
  k_main<<<NB * NF, 128, 0, stream>>>(Xr, Xi, out, out_size);
}

// Round 10
// 193.339 us; speedup vs baseline: 1.5880x; 1.0614x over previous
//
#include <hip/hip_runtime.h>
#include <math.h>

#define NB 4
#define NC 4
#define NF 257
#define NFR 1024
#define NTOT (NB * NC * NF * NFR)
#define NBC (NB * NC)
#define EPSV 1e-3f
#define EPS_MODEL 1e-5f
#define NCHUNK 32

typedef float v2f __attribute__((ext_vector_type(2)));

// Module-scope scratch: allocated at load, graph-capture safe, fully
// rewritten every call.
__device__ float g_Spart[NCHUNK * NBC * NFR];  // partial column sums
__device__ float g_S[NBC * NFR];               // S[b,c,n] = sum_f |X[b,c,f,n]|^2
__device__ float g_gP[96];                     // g_e, P_e per (b,c), e=0..2

// Wave-wide sum via DPP (VALU pipe, no LDS traffic). Lane 63 holds the sum.
__device__ __forceinline__ float dpp_red_sum(float v) {
  v += __int_as_float(__builtin_amdgcn_update_dpp(0, __float_as_int(v), 0x111, 0xf, 0xf, true)); // row_shr:1
  v += __int_as_float(__builtin_amdgcn_update_dpp(0, __float_as_int(v), 0x112, 0xf, 0xf, true)); // row_shr:2
  v += __int_as_float(__builtin_amdgcn_update_dpp(0, __float_as_int(v), 0x114, 0xf, 0xf, true)); // row_shr:4
  v += __int_as_float(__builtin_amdgcn_update_dpp(0, __float_as_int(v), 0x118, 0xf, 0xf, true)); // row_shr:8
  v += __int_as_float(__builtin_amdgcn_update_dpp(0, __float_as_int(v), 0x142, 0xa, 0xf, true)); // row_bcast:15
  v += __int_as_float(__builtin_amdgcn_update_dpp(0, __float_as_int(v), 0x143, 0xc, 0xf, true)); // row_bcast:31
  return v;
}

// ---------------------------------------------------------------------------
// K1: partial column sums, float4-vectorized, 512 blocks (full GPU).
// ---------------------------------------------------------------------------
__global__ __launch_bounds__(256) void k_colsum(const float* __restrict__ Xr,
                                                const float* __restrict__ Xi) {
  int u = blockIdx.x * 256 + threadIdx.x;  // bc*256 + q
  int fc = blockIdx.y;
  int f0 = fc * 9;
  int f1 = f0 + 9; if (f1 > NF) f1 = NF;
  int bc = u >> 8, q = u & 255;
  float4 s = make_float4(0.f, 0.f, 0.f, 0.f);
  for (int f = f0; f < f1; ++f) {
    float4 a = reinterpret_cast<const float4*>(Xr + (bc * NF + f) * NFR)[q];
    float4 b = reinterpret_cast<const float4*>(Xi + (bc * NF + f) * NFR)[q];
    s.x += a.x * a.x + b.x * b.x;
    s.y += a.y * a.y + b.y * b.y;
    s.z += a.z * a.z + b.z * b.z;
    s.w += a.w * a.w + b.w * b.w;
  }
  reinterpret_cast<float4*>(g_Spart + fc * (NBC * NFR) + bc * NFR)[q] = s;
}

// ---------------------------------------------------------------------------
// K2 (fused): reduce 32 partials -> g_S; block-reduce to s0; g_e/P_e table.
// ---------------------------------------------------------------------------
__global__ __launch_bounds__(256) void k_redgp() {
  int bc = blockIdx.x, tid = threadIdx.x;
  float4 s = make_float4(0.f, 0.f, 0.f, 0.f);
#pragma unroll
  for (int fc = 0; fc < NCHUNK; ++fc) {
    float4 a = reinterpret_cast<const float4*>(g_Spart + fc * (NBC * NFR) + bc * NFR)[tid];
    s.x += a.x; s.y += a.y; s.z += a.z; s.w += a.w;
  }
  reinterpret_cast<float4*>(g_S + bc * NFR)[tid] = s;
  float p = dpp_red_sum(s.x + s.y + s.z + s.w);
  __shared__ float r[4];
  if ((tid & 63) == 63) r[tid >> 6] = p;
  __syncthreads();
  if (tid == 0) {
    float s0 = (r[0] + r[1] + r[2] + r[3]) / (float)(NF * NFR);
    float P = 1.f;
#pragma unroll
    for (int e = 0; e < 3; ++e) {
      float g = fmaxf(s0 / P, 1e-5f);
      g_gP[e * 32 + bc] = g;
      g_gP[e * 32 + 16 + bc] = P;
      P *= g;
    }
  }
}

// Block-level reduction of 12 partials, 2-wave version: DPP within wave,
// one barrier, b128 LDS round-trip, double-buffered via `buf`.
__device__ __forceinline__ void block_reduce12(float* __restrict__ p,
                                               float (*red)[2][12], int buf,
                                               int lane, int wvid,
                                               float* __restrict__ s) {
#pragma unroll
  for (int k = 0; k < 12; ++k) p[k] = dpp_red_sum(p[k]);
  if (lane == 63) {
    float4* dst = reinterpret_cast<float4*>(&red[buf][wvid][0]);
    dst[0] = make_float4(p[0], p[1], p[2], p[3]);
    dst[1] = make_float4(p[4], p[5], p[6], p[7]);
    dst[2] = make_float4(p[8], p[9], p[10], p[11]);
  }
  __syncthreads();
  const float4* r = reinterpret_cast<const float4*>(&red[buf][0][0]);
#pragma unroll
  for (int k = 0; k < 3; ++k) {
    float4 a = r[k], b = r[3 + k];
    s[4 * k + 0] = a.x + b.x;
    s[4 * k + 1] = a.y + b.y;
    s[4 * k + 2] = a.z + b.z;
    s[4 * k + 3] = a.w + b.w;
  }
}

// ---------------------------------------------------------------------------
// Main: one block per (b,f), 128 threads (2 waves), 8 frames/thread held as
// 4x v2f (<2 x float>) pairs -> v_pk_fma_f32 codegen for accumulate/update.
// Round-9 structure otherwise; (128,2) bounds (VGPR cap 256, no spills).
// ---------------------------------------------------------------------------
__global__ __launch_bounds__(128, 2) void k_main(const float* __restrict__ Xr,
                                                 const float* __restrict__ Xi,
                                                 float* __restrict__ out, int nout) {
  const int blk = blockIdx.x;
  const int b = blk / NF, f = blk % NF;
  const int tid = threadIdx.x;            // 0..127
  const int lane = tid & 63, wvid = tid >> 6;
  const float invN = 1.f / (float)NFR;

  __shared__ float red[2][2][12];
  __shared__ float Wre[NC][NC], Wim[NC][NC];
  __shared__ float abc[8];

  v2f xcr[NC][4], xci[NC][4];
  int rowbase[NC];
#pragma unroll
  for (int c = 0; c < NC; ++c) {
    rowbase[c] = ((b * NC + c) * NF + f) * NFR;
    const float4* pr = reinterpret_cast<const float4*>(Xr + rowbase[c]);
    const float4* pi = reinterpret_cast<const float4*>(Xi + rowbase[c]);
    float4 a0 = pr[2 * tid], a1 = pr[2 * tid + 1];
    float4 b0 = pi[2 * tid], b1 = pi[2 * tid + 1];
    xcr[c][0] = (v2f){a0.x, a0.y}; xcr[c][1] = (v2f){a0.z, a0.w};
    xcr[c][2] = (v2f){a1.x, a1.y}; xcr[c][3] = (v2f){a1.z, a1.w};
    xci[c][0] = (v2f){b0.x, b0.y}; xci[c][1] = (v2f){b0.z, b0.w};
    xci[c][2] = (v2f){b1.x, b1.y}; xci[c][3] = (v2f){b1.z, b1.w};
  }
  if (tid < 16) {
    Wre[tid >> 2][tid & 3] = ((tid >> 2) == (tid & 3)) ? 1.f : 0.f;
    Wim[tid >> 2][tid & 3] = 0.f;
  }
  // W-init visibility to thread 0: ordered by the first sweep's barrier.

  v2f w2[NC][4];
  int buf = 0;

  for (int e = 0; e < 3; ++e) {
    // ---- per-epoch weights: w = g * rcp(max(2*sqrt(S/P), eps)) ----
#pragma unroll
    for (int c = 0; c < NC; ++c) {
      float g = g_gP[e * 32 + b * NC + c];
      float P = g_gP[e * 32 + 16 + b * NC + c];
      float sc = __builtin_amdgcn_rcpf(P);
      const float4* ps = reinterpret_cast<const float4*>(g_S + (b * NC + c) * NFR);
      float4 S0 = ps[2 * tid], S1 = ps[2 * tid + 1];
      float sv[8] = {S0.x, S0.y, S0.z, S0.w, S1.x, S1.y, S1.z, S1.w};
      float wv[8];
#pragma unroll
      for (int j = 0; j < 8; ++j)
        wv[j] = g * __builtin_amdgcn_rcpf(fmaxf(2.f * __builtin_amdgcn_sqrtf(sv[j] * sc), EPS_MODEL));
#pragma unroll
      for (int h = 0; h < 4; ++h) w2[c][h] = (v2f){wv[2 * h], wv[2 * h + 1]};
    }

    // ================= type-1 sweeps =================
    for (int src = 0; src < NC; ++src) {
      v2f p2[12];
#pragma unroll
      for (int k = 0; k < 12; ++k) p2[k] = (v2f){0.f, 0.f};
#pragma unroll
      for (int h = 0; h < 4; ++h) {
        v2f xsr = xcr[src][h], xsi = xci[src][h];
        v2f msq = xsr * xsr + xsi * xsi;
#pragma unroll
        for (int c = 0; c < NC; ++c) {
          v2f wv = w2[c][h];
          p2[c]     += wv * (xcr[c][h] * xsr + xci[c][h] * xsi);
          p2[4 + c] += wv * (xci[c][h] * xsr - xcr[c][h] * xsi);
          p2[8 + c] += wv * msq;
        }
      }
      float p[12];
#pragma unroll
      for (int k = 0; k < 12; ++k) p[k] = p2[k].x + p2[k].y;
      float s12[12];
      block_reduce12(p, red, buf, lane, wvid, s12);
      buf ^= 1;

      float vr[NC], vi[NC];
#pragma unroll
      for (int c = 0; c < NC; ++c) {
        float den = fmaxf(s12[8 + c] * invN, EPSV);
        if (c == src) {
          vr[c] = 1.f - __builtin_amdgcn_rsqf(den);
          vi[c] = 0.f;
        } else {
          float sc = invN * __builtin_amdgcn_rcpf(den);
          vr[c] = s12[c] * sc;
          vi[c] = s12[4 + c] * sc;
        }
      }
#pragma unroll
      for (int h = 0; h < 4; ++h) {
        v2f xsr = xcr[src][h], xsi = xci[src][h];
#pragma unroll
        for (int c = 0; c < NC; ++c) {
          xcr[c][h] -= xsr * vr[c] - xsi * vi[c];
          xci[c][h] -= xsi * vr[c] + xsr * vi[c];
        }
      }
      if (tid == 0) {
#pragma unroll
        for (int jj = 0; jj < NC; ++jj) {
          float wsr = Wre[src][jj], wsi = Wim[src][jj];
#pragma unroll
          for (int c = 0; c < NC; ++c) {
            Wre[c][jj] -= vr[c] * wsr - vi[c] * wsi;
            Wim[c][jj] -= vr[c] * wsi + vi[c] * wsr;
          }
        }
      }
    }

    // ================= type-2 sweeps =================
    for (int src = 0; src < NC; ++src) {
      const float4* pr = reinterpret_cast<const float4*>(Xr + rowbase[src]);
      const float4* pi = reinterpret_cast<const float4*>(Xi + rowbase[src]);
      // 9-frame window [8t-3 .. 8t+5] of ORIGINAL X serves both taps.
      float4 A4r = make_float4(0.f, 0.f, 0.f, 0.f), A4i = A4r;
      if (tid > 0) { A4r = pr[2 * tid - 1]; A4i = pi[2 * tid - 1]; }
      float4 B4r = pr[2 * tid], B4i = pi[2 * tid];
      float4 C4r = pr[2 * tid + 1], C4i = pi[2 * tid + 1];
      float wr[9] = {A4r.y, A4r.z, A4r.w, B4r.x, B4r.y, B4r.z, B4r.w, C4r.x, C4r.y};
      float wi[9] = {A4i.y, A4i.z, A4i.w, B4i.x, B4i.y, B4i.z, B4i.w, C4i.x, C4i.y};
      for (int tap = 0; tap < 2; ++tap) {
        v2f xs_r[4], xs_i[4];
#pragma unroll
        for (int h = 0; h < 4; ++h) {
          xs_r[h] = (v2f){wr[tap + 2 * h], wr[tap + 2 * h + 1]};
          xs_i[h] = (v2f){wi[tap + 2 * h], wi[tap + 2 * h + 1]};
        }
        v2f p2[12];
#pragma unroll
        for (int k = 0; k < 12; ++k) p2[k] = (v2f){0.f, 0.f};
#pragma unroll
        for (int h = 0; h < 4; ++h) {
          v2f xsr = xs_r[h], xsi = xs_i[h];
          v2f msq = xsr * xsr + xsi * xsi;
#pragma unroll
          for (int c = 0; c < NC; ++c) {
            v2f wv = w2[c][h];
            p2[c]     += wv * (xcr[c][h] * xsr + xci[c][h] * xsi);
            p2[4 + c] += wv * (xci[c][h] * xsr - xcr[c][h] * xsi);
            p2[8 + c] += wv * msq;
          }
        }
        float p[12];
#pragma unroll
        for (int k = 0; k < 12; ++k) p[k] = p2[k].x + p2[k].y;
        float s12[12];
        block_reduce12(p, red, buf, lane, wvid, s12);
        buf ^= 1;

        float vr[NC], vi[NC];
#pragma unroll
        for (int c = 0; c < NC; ++c) {
          float den = fmaxf(s12[8 + c], EPSV);  // SUM, not mean
          float sc = invN * __builtin_amdgcn_rcpf(den);
          vr[c] = s12[c] * sc;
          vi[c] = s12[4 + c] * sc;
        }
#pragma unroll
        for (int h = 0; h < 4; ++h) {
          v2f xsr = xs_r[h], xsi = xs_i[h];
#pragma unroll
          for (int c = 0; c < NC; ++c) {
            xcr[c][h] -= xsr * vr[c] - xsi * vi[c];
            xci[c][h] -= xsi * vr[c] + xsr * vi[c];
          }
        }
      }
    }
  }  // epochs

  // ---- solve W^T a = e1 (4x4 complex, partial pivoting), A[i][j] = W[j][i] ----
  __syncthreads();
  if (tid == 0) {
    float Ar[4][4], Ai[4][4];
    float br[4] = {1.f, 0.f, 0.f, 0.f}, bi[4] = {0.f, 0.f, 0.f, 0.f};
#pragma unroll
    for (int i = 0; i < 4; ++i)
#pragma unroll
      for (int j = 0; j < 4; ++j) {
        Ar[i][j] = Wre[j][i];
        Ai[i][j] = Wim[j][i];
      }
    for (int k = 0; k < 4; ++k) {
      int piv = k;
      float best = Ar[k][k] * Ar[k][k] + Ai[k][k] * Ai[k][k];
      for (int i = k + 1; i < 4; ++i) {
        float m = Ar[i][k] * Ar[i][k] + Ai[i][k] * Ai[i][k];
        if (m > best) { best = m; piv = i; }
      }
      if (piv != k) {
        for (int j = 0; j < 4; ++j) {
          float t = Ar[k][j]; Ar[k][j] = Ar[piv][j]; Ar[piv][j] = t;
          t = Ai[k][j]; Ai[k][j] = Ai[piv][j]; Ai[piv][j] = t;
        }
        float t = br[k]; br[k] = br[piv]; br[piv] = t;
        t = bi[k]; bi[k] = bi[piv]; bi[piv] = t;
      }
      float dr = Ar[k][k], di = Ai[k][k];
      float inv = 1.f / (dr * dr + di * di);
      for (int i = k + 1; i < 4; ++i) {
        float fr = (Ar[i][k] * dr + Ai[i][k] * di) * inv;
        float fi = (Ai[i][k] * dr - Ar[i][k] * di) * inv;
        for (int j = k; j < 4; ++j) {
          Ar[i][j] -= fr * Ar[k][j] - fi * Ai[k][j];
          Ai[i][j] -= fr * Ai[k][j] + fi * Ar[k][j];
        }
        br[i] -= fr * br[k] - fi * bi[k];
        bi[i] -= fr * bi[k] + fi * br[k];
      }
    }
    float ar[4], ai[4];
    for (int k = 3; k >= 0; --k) {
      float sr = br[k], si = bi[k];
      for (int j = k + 1; j < 4; ++j) {
        sr -= Ar[k][j] * ar[j] - Ai[k][j] * ai[j];
        si -= Ar[k][j] * ai[j] + Ai[k][j] * ar[j];
      }
      float dr = Ar[k][k], di = Ai[k][k];
      float inv = 1.f / (dr * dr + di * di);
      ar[k] = (sr * dr + si * di) * inv;
      ai[k] = (si * dr - sr * di) * inv;
    }
#pragma unroll
    for (int c = 0; c < 4; ++c) { abc[c] = ar[c]; abc[4 + c] = ai[c]; }
  }
  __syncthreads();

  // ---- output: real(Xc * a), 2x float4 per (c, thread), bounds-guarded ----
#pragma unroll
  for (int c = 0; c < NC; ++c) {
    float ar = abc[c], ai2 = abc[4 + c];
    if (rowbase[c] + 8 * tid + 7 < nout) {
      float4* po = reinterpret_cast<float4*>(out + rowbase[c]);
      v2f o0 = xcr[c][0] * ar - xci[c][0] * ai2;
      v2f o1 = xcr[c][1] * ar - xci[c][1] * ai2;
      v2f o2 = xcr[c][2] * ar - xci[c][2] * ai2;
      v2f o3 = xcr[c][3] * ar - xci[c][3] * ai2;
      po[2 * tid]     = make_float4(o0.x, o0.y, o1.x, o1.y);
      po[2 * tid + 1] = make_float4(o2.x, o2.y, o3.x, o3.y);
    }
  }
}

// ---------------------------------------------------------------------------
extern "C" void kernel_launch(void* const* d_in, const int* in_sizes, int n_in,
                              void* d_out, int out_size, void* d_ws, size_t ws_size,
                              hipStream_t stream) {
  const float* Xr = (const float*)d_in[0];
  const float* Xi = (const float*)d_in[1];
  float* out = (float*)d_out;

  dim3 g1(16, NCHUNK);
  k_colsum<<<g1, 256, 0, stream>>>(Xr, Xi);
  k_redgp<<<16, 256, 0, stream>>>();
  k_main<<<NB * NF, 128, 0, stream>>>(Xr, Xi, out, out_size);
}